// Round 7
// baseline (90.172 us; speedup 1.0000x reference)
//
#include <hip/hip_runtime.h>
#include <hip/hip_bf16.h>

#define B_ 32
#define N_ 256
#define C_ 512
#define O_ 512
#define S_ 512

#define KT  64     // weight k-tile (floats)
#define WST 72     // wt row stride in shorts: 144 B, 16B-aligned (2 lanes/bank on b128 reads = free)

typedef __attribute__((ext_vector_type(8))) short short8;
typedef __attribute__((ext_vector_type(4))) float f32x4;

// packed f32x2 -> bf16x2 (RNE) — lowers to v_cvt_pk_bf16_f32
__device__ __forceinline__ unsigned pk2(float a, float b) {
    union { __hip_bfloat162 h; unsigned u; } v;
    v.h = __float22bfloat162_rn(make_float2(a, b));
    return v.u;
}

// R4 structure + depth-2 weight prefetch (triple reg rotation) + packed cvt +
// fp32 ssq folded into the commit phase (published via LDS).
__global__ __launch_bounds__(256, 2) void tml_kernel(const float* __restrict__ x,
                                                     const float* __restrict__ s,
                                                     const float* __restrict__ weight,
                                                     const float* __restrict__ bias,
                                                     const float* __restrict__ s_w,
                                                     const float* __restrict__ s_b,
                                                     float* __restrict__ out) {
    // XCD-aware bijective remap (nwg=1024 divisible by 8)
    const int h       = blockIdx.x;
    const int logical = (h & 7) * 128 + (h >> 3);
    const int n       = logical >> 2;
    const int ot      = logical & 3;

    const int tid  = threadIdx.x;
    const int wv   = tid >> 6;
    const int lane = tid & 63;
    const int l16  = lane & 15;
    const int lk   = lane >> 4;
    const int srow = tid >> 4;   // staging row-in-group (0..15)
    const int scol = tid & 15;   // staging 16B slot

    __shared__ short xs[B_][C_ + 8];     // bf16 x (33.3 KB)
    __shared__ short wt[2][128][WST];    // bf16 weight k-tiles, dbuf (36.9 KB)
    __shared__ float ssq_lds[128];       // fp32 sumsq per panel o-row
    __shared__ float sm_lds[B_];

    // thread's slice of tile t: rows i*16+srow, float4 at k-offset t*KT + scol*4
    const float* wbase = weight + (size_t)n * (O_ * C_) + (size_t)(ot * 128) * C_ + scol * 4;

    float4 rgA[8], rgB[8], rgC[8];
    // prologue: tiles 0 and 1 in flight before the smap/x phases
#pragma unroll
    for (int i = 0; i < 8; ++i)
        rgA[i] = *(const float4*)(wbase + (size_t)(i * 16 + srow) * C_);
#pragma unroll
    for (int i = 0; i < 8; ++i)
        rgB[i] = *(const float4*)(wbase + (size_t)(i * 16 + srow) * C_ + KT);

    // ---- fused smap: sm_lds[b] = gain * dot(s[b,:], s_w[n,:]) + s_b[n]
    {
        const int b    = tid >> 3;
        const int slot = tid & 7;
        const float* sp = s   + (size_t)b * S_ + slot * 64;
        const float* wp = s_w + (size_t)n * S_ + slot * 64;
        float sum = 0.f;
#pragma unroll
        for (int j = 0; j < 16; ++j) {
            float4 sv  = *(const float4*)(sp + 4 * j);
            float4 wv4 = *(const float4*)(wp + 4 * j);
            sum += sv.x * wv4.x + sv.y * wv4.y + sv.z * wv4.z + sv.w * wv4.w;
        }
        sum += __shfl_xor(sum, 1, 64);
        sum += __shfl_xor(sum, 2, 64);
        sum += __shfl_xor(sum, 4, 64);
        if (slot == 0) sm_lds[b] = sum * 0.04419417382415922f + s_b[n];
    }

    // ---- stage x[:, n, :] -> bf16 LDS (packed cvt)
    const float* xn = x + (size_t)n * C_;
#pragma unroll
    for (int r = 0; r < 16; ++r) {
        int i  = r * 256 + tid;
        int b  = i >> 7;
        int c4 = (i & 127) << 2;
        const float4 v = *(const float4*)(xn + (size_t)b * (N_ * C_) + c4);
        *(uint2*)&xs[b][c4] = make_uint2(pk2(v.x, v.y), pk2(v.z, v.w));
    }

    float ssqr[8];
#pragma unroll
    for (int i = 0; i < 8; ++i) ssqr[i] = 0.f;

    f32x4 acc00 = {0.f,0.f,0.f,0.f}, acc01 = acc00, acc10 = acc00, acc11 = acc00;

    // STEP T: issue loads for tile T+2; commit tile T (ssq fp32 + packed cvt);
    // barrier; MFMA tile T. Buffer T&1 is next written at commit T+2, which is
    // separated from MFMA T by the STEP T+1 barrier.
#define STEP(T, RC, RN, PB)                                                       \
    {                                                                             \
        if ((T) + 2 < 8) {                                                        \
            _Pragma("unroll")                                                     \
            for (int i = 0; i < 8; ++i)                                           \
                RN[i] = *(const float4*)(wbase + (size_t)(i * 16 + srow) * C_     \
                                         + ((T) + 2) * KT);                       \
        }                                                                         \
        _Pragma("unroll")                                                         \
        for (int i = 0; i < 8; ++i) {                                             \
            ssqr[i] += RC[i].x * RC[i].x + RC[i].y * RC[i].y                      \
                     + RC[i].z * RC[i].z + RC[i].w * RC[i].w;                     \
            *(uint2*)&wt[PB][i * 16 + srow][scol * 4] =                           \
                make_uint2(pk2(RC[i].x, RC[i].y), pk2(RC[i].z, RC[i].w));         \
        }                                                                         \
        if ((T) == 7) {                                                           \
            _Pragma("unroll")                                                     \
            for (int i = 0; i < 8; ++i) {                                         \
                float v = ssqr[i];                                                \
                v += __shfl_xor(v, 1, 64);                                        \
                v += __shfl_xor(v, 2, 64);                                        \
                v += __shfl_xor(v, 4, 64);                                        \
                v += __shfl_xor(v, 8, 64);                                        \
                if (scol == 0) ssq_lds[i * 16 + srow] = v;                        \
            }                                                                     \
        }                                                                         \
        __syncthreads();                                                          \
        _Pragma("unroll")                                                         \
        for (int ks = 0; ks < 2; ++ks) {                                          \
            const int co = ks * 32 + lk * 8;                                      \
            short8 a0 = *(const short8*)&xs[l16][(T) * KT + co];                  \
            short8 a1 = *(const short8*)&xs[16 + l16][(T) * KT + co];             \
            short8 b0 = *(const short8*)&wt[PB][wv * 32 + l16][co];               \
            short8 b1 = *(const short8*)&wt[PB][wv * 32 + 16 + l16][co];          \
            acc00 = __builtin_amdgcn_mfma_f32_16x16x32_bf16(a0, b0, acc00, 0,0,0);\
            acc10 = __builtin_amdgcn_mfma_f32_16x16x32_bf16(a1, b0, acc10, 0,0,0);\
            acc01 = __builtin_amdgcn_mfma_f32_16x16x32_bf16(a0, b1, acc01, 0,0,0);\
            acc11 = __builtin_amdgcn_mfma_f32_16x16x32_bf16(a1, b1, acc11, 0,0,0);\
        }                                                                         \
    }

    // tile t lives in reg set t%3; STEP T loads tile T+2 into set (T+2)%3
    STEP(0, rgA, rgC, 0)
    STEP(1, rgB, rgA, 1)
    STEP(2, rgC, rgB, 0)
    STEP(3, rgA, rgC, 1)
    STEP(4, rgB, rgA, 0)
    STEP(5, rgC, rgB, 1)
    STEP(6, rgA, rgC, 0)
    STEP(7, rgB, rgC, 1)
#undef STEP

    // ---- epilogue. C/D layout: col = lane&15, row = (lane>>4)*4 + reg
#pragma unroll
    for (int f = 0; f < 2; ++f) {
        const int orow = wv * 32 + f * 16 + l16;       // panel-local o row
        const int o    = ot * 128 + orow;
        const float bv = bias[n * O_ + o];
        const float sq = ssq_lds[orow];
        const f32x4 am0 = f ? acc01 : acc00;
        const f32x4 am1 = f ? acc11 : acc10;
#pragma unroll
        for (int r = 0; r < 4; ++r) {
            {
                const int brow = lk * 4 + r;
                const float smv = sm_lds[brow];
                const float dec = rsqrtf(smv * smv * sq + 1e-8f);
                out[(size_t)brow * (N_ * O_) + n * O_ + o] = am0[r] * smv * dec + bv;
            }
            {
                const int brow = 16 + lk * 4 + r;
                const float smv = sm_lds[brow];
                const float dec = rsqrtf(smv * smv * sq + 1e-8f);
                out[(size_t)brow * (N_ * O_) + n * O_ + o] = am1[r] * smv * dec + bv;
            }
        }
    }
}

extern "C" void kernel_launch(void* const* d_in, const int* in_sizes, int n_in,
                              void* d_out, int out_size, void* d_ws, size_t ws_size,
                              hipStream_t stream) {
    const float* x      = (const float*)d_in[0];
    const float* s      = (const float*)d_in[1];
    const float* weight = (const float*)d_in[2];
    const float* bias   = (const float*)d_in[3];
    const float* s_w    = (const float*)d_in[4];
    const float* s_b    = (const float*)d_in[5];
    float* out = (float*)d_out;

    tml_kernel<<<N_ * 4, 256, 0, stream>>>(x, s, weight, bias, s_w, s_b, out);
}